// Round 16
// baseline (625.019 us; speedup 1.0000x reference)
//
#include <hip/hip_runtime.h>
#include <cstdint>
#include <cstddef>

#define DM   2048   // D_MODEL
#define DI   4096   // D_INNER
#define DST  16     // D_STATE
#define DTR  128    // DT_RANK
#define SEQL 2048
#define NTOK 4096   // B_SZ * SEQ
#define XZW  8192   // 2*D_INNER
#define NCHAIN 8192 // B_SZ * D_INNER
#define CL   32     // scan chunk length
#define NCH  64     // number of chunks (SEQL / CL)

typedef short short8 __attribute__((ext_vector_type(8)));
typedef float f32x4 __attribute__((ext_vector_type(4)));

__device__ __forceinline__ short f2bf(float x) {
  union { float f; uint32_t u; } v; v.f = x;
  uint32_t r = v.u + 0x7fffu + ((v.u >> 16) & 1u);
  return (short)(r >> 16);
}
__device__ __forceinline__ float bf2f(short s) {
  union { uint32_t u; float f; } v; v.u = ((uint32_t)(uint16_t)s) << 16;
  return v.f;
}

__device__ __forceinline__ void stage16(const short* g, short* l) {
#if __has_builtin(__builtin_amdgcn_global_load_lds)
  __builtin_amdgcn_global_load_lds((const __attribute__((address_space(1))) void*)g,
                                   (__attribute__((address_space(3))) void*)l, 16, 0, 0);
#else
  *(short8*)l = *(const short8*)g;
#endif
}

// ---- fused prep: weight conversions (win,wout,wdt,xp-pad) + RMSNorm ----
#define NG_WIN  (XZW * DM / 4)
#define NG_WOUT (DM * DI / 4)
#define NG_WDT  (DI * DTR / 4)
#define NG_PAD  (256 * DI / 4)
#define NG_ALL  (NG_WIN + NG_WOUT + NG_WDT + NG_PAD)
#define NB_CVT  (NG_ALL / 256)           // 26112 blocks
__global__ __launch_bounds__(256) void prep_k(const float* __restrict__ win,
                                              const float* __restrict__ wout,
                                              const float* __restrict__ wdt,
                                              const float* __restrict__ xp,
                                              const float* __restrict__ hs,
                                              const float* __restrict__ nsc,
                                              short* __restrict__ win_bf,
                                              short* __restrict__ wout_bf,
                                              short* __restrict__ wdt_bf,
                                              short* __restrict__ wxp_bf,
                                              short* __restrict__ xn_bf) {
  const int blk = blockIdx.x;
  const int tid = threadIdx.x;
  if (blk < NB_CVT) {
    const size_t i = (size_t)blk * 256 + tid;
    float4 v;
    short4* dst;
    if (i < NG_WIN) {
      v = ((const float4*)win)[i];
      dst = (short4*)win_bf + i;
    } else if (i < NG_WIN + NG_WOUT) {
      const size_t j = i - NG_WIN;
      v = ((const float4*)wout)[j];
      dst = (short4*)wout_bf + j;
    } else if (i < NG_WIN + NG_WOUT + NG_WDT) {
      const size_t j = i - NG_WIN - NG_WOUT;
      v = ((const float4*)wdt)[j];
      dst = (short4*)wdt_bf + j;
    } else {
      const size_t j = i - NG_WIN - NG_WOUT - NG_WDT;
      const int r = (int)(j >> 10);
      v = (r < 160) ? ((const float4*)xp)[j] : make_float4(0.f, 0.f, 0.f, 0.f);
      dst = (short4*)wxp_bf + j;
    }
    short4 o;
    o.x = f2bf(v.x); o.y = f2bf(v.y); o.z = f2bf(v.z); o.w = f2bf(v.w);
    *dst = o;
  } else {
    const int token = blk - NB_CVT;
    const float* row = hs + (size_t)token * DM;
    float4 a = ((const float4*)row)[tid];
    float4 b = ((const float4*)row)[tid + 256];
    float ss = a.x*a.x + a.y*a.y + a.z*a.z + a.w*a.w
             + b.x*b.x + b.y*b.y + b.z*b.z + b.w*b.w;
    #pragma unroll
    for (int o = 32; o > 0; o >>= 1) ss += __shfl_xor(ss, o);
    __shared__ float wsum[4];
    if ((tid & 63) == 0) wsum[tid >> 6] = ss;
    __syncthreads();
    float tot = wsum[0] + wsum[1] + wsum[2] + wsum[3];
    float inv = rsqrtf(tot * (1.0f / DM) + 1e-5f);
    float4 s1 = ((const float4*)nsc)[tid];
    float4 s2 = ((const float4*)nsc)[tid + 256];
    short4 o1, o2;
    o1.x = f2bf(a.x * inv * s1.x); o1.y = f2bf(a.y * inv * s1.y);
    o1.z = f2bf(a.z * inv * s1.z); o1.w = f2bf(a.w * inv * s1.w);
    o2.x = f2bf(b.x * inv * s2.x); o2.y = f2bf(b.y * inv * s2.y);
    o2.z = f2bf(b.z * inv * s2.z); o2.w = f2bf(b.w * inv * s2.w);
    ((short4*)xn_bf)[(size_t)token * (DM / 4) + tid] = o1;
    ((short4*)xn_bf)[(size_t)token * (DM / 4) + tid + 256] = o2;
  }
}

// ======== 256x256 MFMA GEMM, R12 4-phase + cross-tile PRE schedule, NT ========
// C[m][n] = sum_k A[m][k]*B[n][k].  A: M x K bf16, B: N x K bf16, row-major.
// BM=BN=256, BK=64, 512 threads (2x4 waves). LDS XOR swizzle both-sides.
// Split-K via blockIdx.y. EPI: 0 = f32 store; 1 = softplus(v+aux[col]) -> bf16.
#define LGKM_FENCE() do { asm volatile("s_waitcnt lgkmcnt(0)" ::: "memory"); \
                          __builtin_amdgcn_sched_barrier(0); } while (0)

template <int RBY, int RBX, int EPI>
__global__ __launch_bounds__(512) void gemm_big(const short* __restrict__ A,
                                                const short* __restrict__ B,
                                                int K, int ksz, int N, int nbx,
                                                float* __restrict__ out_f,
                                                size_t zstride,
                                                const float* __restrict__ aux,
                                                short* __restrict__ out_bf) {
  constexpr int MFR = 8;
  constexpr int BM = 256;
  constexpr int ABYTES = BM * 128;       // 32 KB
  constexpr int BBYTES = 256 * 128;      // 32 KB
  constexpr int BUF = ABYTES + BBYTES;
  constexpr int FPP = 4;
  __shared__ char lds[2 * BUF];

  const int tid = threadIdx.x;
  const int lane = tid & 63;
  const int wid = tid >> 6;
  const int wm = wid >> 2;      // 0..1
  const int wn = wid & 3;       // 0..3
  const int lr = lane & 15;
  const int lj = lane >> 4;

  // XCD square-region mapping
  const int xcd = blockIdx.x & 7;
  const int idx = blockIdx.x >> 3;
  const int nrgx = nbx / RBX;
  const int by = (xcd / nrgx) * RBY + idx / RBX;
  const int bx = (xcd % nrgx) * RBX + idx % RBX;
  const size_t m0 = (size_t)by * BM;
  const size_t n0 = (size_t)bx * 256;

  const int kbase = blockIdx.y * ksz;
  out_f += (size_t)blockIdx.y * zstride;
  const int NT = ksz >> 6;

  auto stA1 = [&](int t, char* buf, int s) {
    const int k0 = kbase + (t << 6);
    const int off = s * 8192 + tid * 16;
    const int r = off >> 7;
    const int j = (off >> 4) & 7;
    stage16(A + (m0 + r) * (size_t)K + k0 + ((j ^ (r & 7)) << 3),
            (short*)(buf + off));
  };
  auto stB1 = [&](int t, char* buf, int s) {
    const int k0 = kbase + (t << 6);
    const int off = s * 8192 + tid * 16;
    const int r = off >> 7;
    const int j = (off >> 4) & 7;
    stage16(B + (n0 + r) * (size_t)K + k0 + ((j ^ (r & 7)) << 3),
            (short*)(buf + ABYTES + off));
  };

#define READ_A(dst, fbase)                                                   \
  _Pragma("unroll")                                                          \
  for (int f = 0; f < 4; ++f) {                                              \
    const int arow = wm * (BM / 2) + ((fbase) + f) * 16 + lr;                \
    _Pragma("unroll")                                                        \
    for (int ks = 0; ks < 2; ++ks)                                           \
      dst[f][ks] = *(const short8*)(cur + arow * 128 +                       \
                     ((((ks << 2) + lj) ^ (arow & 7)) << 4));                \
  }
#define READ_B(dst, gbase)                                                   \
  _Pragma("unroll")                                                          \
  for (int g = 0; g < 2; ++g) {                                              \
    const int brow = wn * 64 + ((gbase) + g) * 16 + lr;                      \
    _Pragma("unroll")                                                        \
    for (int ks = 0; ks < 2; ++ks)                                           \
      dst[g][ks] = *(const short8*)(cur + ABYTES + brow * 128 +              \
                     ((((ks << 2) + lj) ^ (brow & 7)) << 4));                \
  }
#define MFMA_Q(accoff, avoff, gbase, bvx)                                    \
  __builtin_amdgcn_s_setprio(1);                                             \
  _Pragma("unroll")                                                          \
  for (int ks = 0; ks < 2; ++ks)                                             \
    _Pragma("unroll")                                                        \
    for (int f = 0; f < FPP; ++f)                                            \
      _Pragma("unroll")                                                      \
      for (int g = 0; g < 2; ++g)                                            \
        acc[(accoff) + f][(gbase) + g] = __builtin_amdgcn_mfma_f32_16x16x32_bf16( \
            av[(avoff) + f][ks], bvx[g][ks], acc[(accoff) + f][(gbase) + g], 0, 0, 0); \
  __builtin_amdgcn_s_setprio(0);

  f32x4 acc[MFR][4] = {};

  // prologue: tile 0 fully; pre-issue tile 1's A-lo regions
  {
    #pragma unroll
    for (int s = 0; s < 4; ++s) stA1(0, lds, s);
    #pragma unroll
    for (int s = 0; s < 4; ++s) stB1(0, lds, s);
    if (NT > 1) {
      stA1(1, lds + BUF, 0); stA1(1, lds + BUF, 2);
      asm volatile("s_waitcnt vmcnt(2)" ::: "memory");
    } else asm volatile("s_waitcnt vmcnt(0)" ::: "memory");
    __builtin_amdgcn_s_barrier();
    __builtin_amdgcn_sched_barrier(0);
  }

  for (int t = 0; t < NT; ++t) {
    char* cur = lds + (t & 1) * BUF;
    char* nxt = lds + ((t + 1) & 1) * BUF;
    const bool m1 = (t + 1) < NT;
    const bool m2 = (t + 2) < NT;
    short8 av[4][2], bv0[2][2], bv1[2][2];

    // ---- phase 0: read A0 + B0; stage A(t+1) hi regions
    READ_A(av, 0);
    READ_B(bv0, 0);
    if (m1) { stA1(t + 1, nxt, 1); stA1(t + 1, nxt, 3); }
    LGKM_FENCE();
    MFMA_Q(0, 0, 0, bv0);
    __builtin_amdgcn_s_barrier();

    // ---- phase 1: read B1; stage B_lo(t+1)
    READ_B(bv1, 2);
    if (m1) { stB1(t + 1, nxt, 0); stB1(t + 1, nxt, 1); }
    LGKM_FENCE();
    MFMA_Q(0, 0, 2, bv1);
    __builtin_amdgcn_s_barrier();

    // ---- phase 2: read A1; stage B_hi(t+1); pre-issue A_lo(t+2) into cur
    READ_A(av, 4);
    if (m1) { stB1(t + 1, nxt, 2); stB1(t + 1, nxt, 3); }
    if (m2) { stA1(t + 2, cur, 0); stA1(t + 2, cur, 2); }
    LGKM_FENCE();
    MFMA_Q(4, 0, 2, bv1);
    __builtin_amdgcn_s_barrier();

    // ---- phase 3: MFMA A1 x B0 (reg-cached); publish with counted vmcnt
    MFMA_Q(4, 0, 0, bv0);
    if (m2) asm volatile("s_waitcnt vmcnt(2)" ::: "memory");
    else    asm volatile("s_waitcnt vmcnt(0)" ::: "memory");
    __builtin_amdgcn_s_barrier();
    __builtin_amdgcn_sched_barrier(0);
  }

  #pragma unroll
  for (int f = 0; f < MFR; ++f)
    #pragma unroll
    for (int g = 0; g < 4; ++g)
      #pragma unroll
      for (int jj = 0; jj < 4; ++jj) {
        const size_t row = m0 + wm * (BM / 2) + f * 16 + lj * 4 + jj;
        const size_t col = n0 + wn * 64 + g * 16 + lr;
        if constexpr (EPI == 0) {
          out_f[row * (size_t)N + col] = acc[f][g][jj];
        } else {
          float x = acc[f][g][jj] + aux[col];
          float sp = (x > 20.f) ? x : log1pf(__expf(x));
          out_bf[row * (size_t)N + col] = f2bf(sp);
        }
      }
#undef READ_A
#undef READ_B
#undef MFMA_Q
}

// ---- out_proj combine: out0 = residual + partial0 + partial1 ----
__global__ __launch_bounds__(256) void combine_k(const float* __restrict__ part,
                                                 const float* __restrict__ hs,
                                                 float* __restrict__ out0) {
  const size_t i = (size_t)blockIdx.x * 256 + threadIdx.x;   // float4 index
  const float4 p0 = ((const float4*)part)[i];
  const float4 p1 = ((const float4*)part)[i + (size_t)NTOK * DM / 4];
  const float4 r  = ((const float4*)hs)[i];
  float4 o;
  o.x = r.x + p0.x + p1.x; o.y = r.y + p0.y + p1.y;
  o.z = r.z + p0.z + p1.z; o.w = r.w + p0.w + p1.w;
  ((float4*)out0)[i] = o;
}

// ---------------- small NT bf16 MFMA GEMM, 128x128x64 tile ----------------
// EPI 4: store f32 partial at out_f[(z*NTOK + row)*N + col], col<160 only
__global__ __launch_bounds__(256) void gemm_nt4(const short* __restrict__ A,
                                                const short* __restrict__ B,
                                                int ld, int K, int N,
                                                float* __restrict__ out_f) {
  __shared__ short As[128 * 64];
  __shared__ short Bs[128 * 64];
  const int tid = threadIdx.x;
  const int lane = tid & 63;
  const int wid = tid >> 6;
  const int wr = wid >> 1, wc = wid & 1;
  const size_t m0 = (size_t)blockIdx.y * 128;
  const size_t n0 = (size_t)blockIdx.x * 128;
  A += (size_t)blockIdx.z * K;
  B += (size_t)blockIdx.z * K;
  f32x4 acc[4][4] = {};
  for (int k0 = 0; k0 < K; k0 += 64) {
    #pragma unroll
    for (int i = 0; i < 4; ++i) {
      const int off = i * 4096 + tid * 16;   // byte offset in 16KB tile
      const int r = off >> 7;                // tile row (128B per row)
      const int ke = (off & 127) >> 1;       // element offset in row
      stage16(A + (m0 + r) * (size_t)ld + k0 + ke, &As[off >> 1]);
      stage16(B + (n0 + r) * (size_t)ld + k0 + ke, &Bs[off >> 1]);
    }
    __syncthreads();
    #pragma unroll
    for (int kk = 0; kk < 64; kk += 32) {
      short8 af[4], bfr[4];
      const int kb = kk + (lane >> 4) * 8;
      const int rr = lane & 15;
      #pragma unroll
      for (int f = 0; f < 4; ++f) {
        af[f]  = *(const short8*)&As[(wr * 64 + f * 16 + rr) * 64 + kb];
        bfr[f] = *(const short8*)&Bs[(wc * 64 + f * 16 + rr) * 64 + kb];
      }
      #pragma unroll
      for (int fm = 0; fm < 4; ++fm)
        #pragma unroll
        for (int fn = 0; fn < 4; ++fn)
          acc[fm][fn] = __builtin_amdgcn_mfma_f32_16x16x32_bf16(af[fm], bfr[fn], acc[fm][fn], 0, 0, 0);
    }
    __syncthreads();
  }
  const int rbase = (lane >> 4) * 4;
  const int cbase = lane & 15;
  #pragma unroll
  for (int fm = 0; fm < 4; ++fm) {
    #pragma unroll
    for (int fn = 0; fn < 4; ++fn) {
      #pragma unroll
      for (int j = 0; j < 4; ++j) {
        const size_t row = m0 + wr * 64 + fm * 16 + rbase + j;
        const size_t col = n0 + wc * 64 + fn * 16 + cbase;
        if (col < 160)
          out_f[((size_t)blockIdx.z * NTOK + row) * (size_t)N + col] = acc[fm][fn][j];
      }
    }
  }
}

// ---- x_dbl epilogue: sum 4 split-K partials, split into dt_low/B/C ----
__global__ __launch_bounds__(256) void xdbl_epi_k(const float* __restrict__ part,
                                                  short* __restrict__ dtl,
                                                  float* __restrict__ Bc,
                                                  float* __restrict__ Cc) {
  const int row = blockIdx.x;
  const int col = threadIdx.x;
  if (col >= 160) return;
  const size_t i = (size_t)row * 256 + col;
  const float v = part[i] + part[(size_t)NTOK * 256 + i]
                + part[(size_t)2 * NTOK * 256 + i]
                + part[(size_t)3 * NTOK * 256 + i];
  if (col < 128)      dtl[(size_t)row * 128 + col] = f2bf(v);
  else if (col < 144) Bc[(size_t)row * 16 + (col - 128)] = v;
  else                Cc[(size_t)row * 16 + (col - 144)] = v;
}

// ------- causal depthwise conv (W=4) + SiLU, rolling window, 8 tok/thread -------
__global__ __launch_bounds__(256) void conv_silu_k(const float* __restrict__ xz,
                                                   const float* __restrict__ cw,
                                                   const float* __restrict__ cb,
                                                   short* __restrict__ xc) {
  const int d = blockIdx.x * 256 + threadIdx.x;
  const int t0 = blockIdx.y * 8;          // global token base (never crosses seq)
  const int l0 = t0 & (SEQL - 1);         // within-sequence index
  const float4 w = ((const float4*)cw)[d];
  const float bias = cb[d];
  float x0 = (l0 >= 3) ? xz[(size_t)(t0 - 3) * XZW + d] : 0.f;
  float x1 = (l0 >= 2) ? xz[(size_t)(t0 - 2) * XZW + d] : 0.f;
  float x2 = (l0 >= 1) ? xz[(size_t)(t0 - 1) * XZW + d] : 0.f;
  #pragma unroll
  for (int i = 0; i < 8; ++i) {
    const float x3 = xz[(size_t)(t0 + i) * XZW + d];
    const float acc = bias + w.x * x0 + w.y * x1 + w.z * x2 + w.w * x3;
    const float sv = acc / (1.f + __expf(-acc));
    xc[(size_t)(t0 + i) * DI + d] = f2bf(sv);
    x0 = x1; x1 = x2; x2 = x3;
  }
}

// -------- chunked selective scan: 1 thread/chain, 16 states/thread --------
// t = chunk*NCHAIN + chain; 524,288 threads for pass 1/3.
#define H_STEP(hj, Aj, Bv)  hj = hj * __expf(delta * Aj) + du * Bv

__global__ __launch_bounds__(256) void scan1_k(const short* __restrict__ del_bf,
                                               const short* __restrict__ xc,
                                               const float* __restrict__ Bc,
                                               const float* __restrict__ alog,
                                               float* __restrict__ hloc,
                                               float* __restrict__ Ssum) {
  const int t = blockIdx.x * 256 + threadIdx.x;
  const int chain = t & (NCHAIN - 1);
  const int chunk = t >> 13;
  const int b = chain >> 12;
  const int d = chain & 4095;
  float A[16];
  #pragma unroll
  for (int j = 0; j < 16; ++j) A[j] = -__expf(alog[d * 16 + j]);
  float h[16] = {};
  float S = 0.f;
  size_t token = (size_t)b * SEQL + (size_t)chunk * CL;
  #pragma unroll 2
  for (int l = 0; l < CL; ++l, ++token) {
    const float delta = bf2f(del_bf[token * DI + d]);
    const float u = bf2f(xc[token * DI + d]);
    const float du = delta * u;
    S += delta;
    const float4 B0 = ((const float4*)Bc)[token * 4 + 0];
    H_STEP(h[0], A[0], B0.x); H_STEP(h[1], A[1], B0.y);
    H_STEP(h[2], A[2], B0.z); H_STEP(h[3], A[3], B0.w);
    const float4 B1 = ((const float4*)Bc)[token * 4 + 1];
    H_STEP(h[4], A[4], B1.x); H_STEP(h[5], A[5], B1.y);
    H_STEP(h[6], A[6], B1.z); H_STEP(h[7], A[7], B1.w);
    const float4 B2 = ((const float4*)Bc)[token * 4 + 2];
    H_STEP(h[8], A[8], B2.x); H_STEP(h[9], A[9], B2.y);
    H_STEP(h[10], A[10], B2.z); H_STEP(h[11], A[11], B2.w);
    const float4 B3 = ((const float4*)Bc)[token * 4 + 3];
    H_STEP(h[12], A[12], B3.x); H_STEP(h[13], A[13], B3.y);
    H_STEP(h[14], A[14], B3.z); H_STEP(h[15], A[15], B3.w);
  }
  const size_t idx = (size_t)(chunk * NCHAIN + chain) * 4;
  ((float4*)hloc)[idx + 0] = make_float4(h[0], h[1], h[2], h[3]);
  ((float4*)hloc)[idx + 1] = make_float4(h[4], h[5], h[6], h[7]);
  ((float4*)hloc)[idx + 2] = make_float4(h[8], h[9], h[10], h[11]);
  ((float4*)hloc)[idx + 3] = make_float4(h[12], h[13], h[14], h[15]);
  Ssum[chunk * NCHAIN + chain] = S;
}

// pass 2: serial combine over chunks, IN-PLACE (hloc[c] becomes h_in[c])
__global__ __launch_bounds__(256) void scan2_k(float* __restrict__ hloc,
                                               const float* __restrict__ Ssum,
                                               const float* __restrict__ alog) {
  const int t = blockIdx.x * 256 + threadIdx.x;   // 32768 threads
  const int q = t & 3;
  const int chain = t >> 2;
  const int d = chain & 4095;
  float A[4];
  #pragma unroll
  for (int j = 0; j < 4; ++j) A[j] = -__expf(alog[d * 16 + q * 4 + j]);
  float4 h = make_float4(0.f, 0.f, 0.f, 0.f);
  for (int c = 0; c < NCH; ++c) {
    const size_t idx = (size_t)(c * NCHAIN + chain) * 4 + q;
    const float S = Ssum[c * NCHAIN + chain];
    const float4 hl = ((const float4*)hloc)[idx];
    ((float4*)hloc)[idx] = h;                 // publish prefix state
    h.x = h.x * __expf(A[0] * S) + hl.x;
    h.y = h.y * __expf(A[1] * S) + hl.y;
    h.z = h.z * __expf(A[2] * S) + hl.z;
    h.w = h.w * __expf(A[3] * S) + hl.w;
  }
}

// pass 3: re-scan chunk from h_in, y + D-skip + z-gate -> y bf16
__global__ __launch_bounds__(256) void scan3_k(const short* __restrict__ del_bf,
                                               const short* __restrict__ xc,
                                               const float* __restrict__ Bc,
                                               const float* __restrict__ Cc,
                                               const float* __restrict__ xzbuf,
                                               const float* __restrict__ alog,
                                               const float* __restrict__ dvec,
                                               const float* __restrict__ hin,
                                               short* __restrict__ y) {
  const int t = blockIdx.x * 256 + threadIdx.x;
  const int chain = t & (NCHAIN - 1);
  const int chunk = t >> 13;
  const int b = chain >> 12;
  const int d = chain & 4095;
  float A[16];
  #pragma unroll
  for (int j = 0; j < 16; ++j) A[j] = -__expf(alog[d * 16 + j]);
  const float Dd = dvec[d];
  const size_t idx = (size_t)(chunk * NCHAIN + chain) * 4;
  float h[16];
  {
    const float4 h0 = ((const float4*)hin)[idx + 0];
    const float4 h1 = ((const float4*)hin)[idx + 1];
    const float4 h2 = ((const float4*)hin)[idx + 2];
    const float4 h3 = ((const float4*)hin)[idx + 3];
    h[0]=h0.x; h[1]=h0.y; h[2]=h0.z; h[3]=h0.w;
    h[4]=h1.x; h[5]=h1.y; h[6]=h1.z; h[7]=h1.w;
    h[8]=h2.x; h[9]=h2.y; h[10]=h2.z; h[11]=h2.w;
    h[12]=h3.x; h[13]=h3.y; h[14]=h3.z; h[15]=h3.w;
  }
  size_t token = (size_t)b * SEQL + (size_t)chunk * CL;
  #pragma unroll 2
  for (int l = 0; l < CL; ++l, ++token) {
    const float delta = bf2f(del_bf[token * DI + d]);
    const float u = bf2f(xc[token * DI + d]);
    const float du = delta * u;
    float yp = 0.f;
    {
      const float4 B0 = ((const float4*)Bc)[token * 4 + 0];
      const float4 C0 = ((const float4*)Cc)[token * 4 + 0];
      H_STEP(h[0], A[0], B0.x); yp += h[0] * C0.x;
      H_STEP(h[1], A[1], B0.y); yp += h[1] * C0.y;
      H_STEP(h[2], A[2], B0.z); yp += h[2] * C0.z;
      H_STEP(h[3], A[3], B0.w); yp += h[3] * C0.w;
    }
    {
      const float4 B1 = ((const float4*)Bc)[token * 4 + 1];
      const float4 C1 = ((const float4*)Cc)[token * 4 + 1];
      H_STEP(h[4], A[4], B1.x); yp += h[4] * C1.x;
      H_STEP(h[5], A[5], B1.y); yp += h[5] * C1.y;
      H_STEP(h[6], A[6], B1.z); yp += h[6] * C1.z;
      H_STEP(h[7], A[7], B1.w); yp += h[7] * C1.w;
    }
    {
      const float4 B2 = ((const float4*)Bc)[token * 4 + 2];
      const float4 C2 = ((const float4*)Cc)[token * 4 + 2];
      H_STEP(h[8], A[8], B2.x);  yp += h[8] * C2.x;
      H_STEP(h[9], A[9], B2.y);  yp += h[9] * C2.y;
      H_STEP(h[10], A[10], B2.z); yp += h[10] * C2.z;
      H_STEP(h[11], A[11], B2.w); yp += h[11] * C2.w;
    }
    {
      const float4 B3 = ((const float4*)Bc)[token * 4 + 3];
      const float4 C3 = ((const float4*)Cc)[token * 4 + 3];
      H_STEP(h[12], A[12], B3.x); yp += h[12] * C3.x;
      H_STEP(h[13], A[13], B3.y); yp += h[13] * C3.y;
      H_STEP(h[14], A[14], B3.z); yp += h[14] * C3.z;
      H_STEP(h[15], A[15], B3.w); yp += h[15] * C3.w;
    }
    const float z = xzbuf[token * XZW + DI + d];
    const float sz = z / (1.f + __expf(-z));
    y[token * DI + d] = f2bf((yp + u * Dd) * sz);
  }
}

extern "C" void kernel_launch(void* const* d_in, const int* in_sizes, int n_in,
                              void* d_out, int out_size, void* d_ws, size_t ws_size,
                              hipStream_t stream) {
  const float* hs   = (const float*)d_in[0];   // (B,L,2048)
  const float* nsc  = (const float*)d_in[1];
  const float* win  = (const float*)d_in[2];   // (8192,2048)
  const float* cw   = (const float*)d_in[3];   // (4096,1,4)
  const float* cb   = (const float*)d_in[4];
  const float* wxp  = (const float*)d_in[5];   // (160,4096)
  const float* wdt  = (const float*)d_in[6];   // (4096,128)
  const float* bdt  = (const float*)d_in[7];
  const float* wout = (const float*)d_in[8];   // (2048,4096)
  const float* alog = (const float*)d_in[9];   // (4096,16)
  const float* dvec = (const float*)d_in[10];

  float* out0 = (float*)d_out;                       // (4096, 2048)
  float* xz   = out0 + (size_t)NTOK * DM;            // (4096, 8192)

  char* w = (char*)d_ws;
  size_t off = 0;
  auto alloc = [&](size_t bytes) {
    char* p = w + off;
    off += (bytes + 255) & ~(size_t)255;
    return p;
  };
  short* xn_bf   = (short*)alloc((size_t)NTOK * DM * 2);      // dead after gemm_big(in_proj)
  short* win_bf  = (short*)alloc((size_t)XZW * DM * 2);       // dead after gemm_big(in_proj)
  short* wout_bf = (short*)alloc((size_t)DM * DI * 2);
  short* wdt_bf  = (short*)alloc((size_t)DI * DTR * 2);
  short* wxp_bf  = (short*)alloc((size_t)256 * DI * 2);
  short* xc_bf   = (short*)alloc((size_t)NTOK * DI * 2);      // dead after scan3
  short* dtl_bf  = (short*)alloc((size_t)NTOK * DTR * 2);     // dead after dt_proj
  float* Bc      = (float*)alloc((size_t)NTOK * DST * 4);     // dead after scan3
  float* Cc      = (float*)alloc((size_t)NTOK * DST * 4);     // dead after scan3
  short* del_bf  = (short*)alloc((size_t)NTOK * DI * 2);      // dead after scan3
  short* y_bf    = (short*)alloc((size_t)NTOK * DI * 2);

  // Aliased scratch (lifetimes disjoint within one call):
  float* xp_part = (float*)win_bf;
  float* hloc    = (float*)win_bf;
  float* Ssum    = (float*)xn_bf;
  float* opart   = (float*)xc_bf;

  // 0+1. fused weight conversions + RMSNorm
  prep_k<<<NB_CVT + NTOK, 256, 0, stream>>>(
      win, wout, wdt, wxp, hs, nsc, win_bf, wout_bf, wdt_bf, wxp_bf, xn_bf);
  // 2. xz = xn @ in_proj^T  -> d_out (output 1)
  gemm_big<8, 8, 0><<<dim3((XZW / 256) * (NTOK / 256)), 512, 0, stream>>>(
      xn_bf, win_bf, DM, DM, XZW, XZW / 256, xz, 0, nullptr, nullptr);
  // 3. causal depthwise conv + SiLU
  conv_silu_k<<<dim3(DI / 256, NTOK / 8), 256, 0, stream>>>(xz, cw, cb, xc_bf);
  // 4. x_dbl = xc @ x_proj^T, split-K x4 -> partials (160 cols) -> dt_low/B/C
  gemm_nt4<<<dim3(2, NTOK / 128, 4), 256, 0, stream>>>(
      xc_bf, wxp_bf, DI, DI / 4, 256, xp_part);
  xdbl_epi_k<<<NTOK, 256, 0, stream>>>(xp_part, dtl_bf, Bc, Cc);
  // 5. delta = softplus(dt_low @ dt_proj^T + b) -> bf16  [256x256 schedule]
  gemm_big<8, 4, 1><<<dim3((DI / 256) * (NTOK / 256)), 512, 0, stream>>>(
      dtl_bf, wdt_bf, DTR, DTR, DI, DI / 256, nullptr, 0, bdt, del_bf);
  // 6. chunked selective scan + gating -> y bf16  (1 thread/chain, 16 states)
  scan1_k<<<(NCHAIN * NCH) / 256, 256, 0, stream>>>(
      del_bf, xc_bf, Bc, alog, hloc, Ssum);
  scan2_k<<<(NCHAIN * 4) / 256, 256, 0, stream>>>(hloc, Ssum, alog);
  scan3_k<<<(NCHAIN * NCH) / 256, 256, 0, stream>>>(
      del_bf, xc_bf, Bc, Cc, xz, alog, dvec, hloc, y_bf);
  // 7. out_proj via split-K=2: 128 tiles x 2 K-halves = 256 blocks
  gemm_big<4, 4, 0><<<dim3((DM / 256) * (NTOK / 256), 2), 512, 0, stream>>>(
      y_bf, wout_bf, DI, DI / 2, DM, DM / 256, opart, (size_t)NTOK * DM,
      nullptr, nullptr);
  combine_k<<<(NTOK * DM / 4) / 256, 256, 0, stream>>>(opart, hs, out0);
}

// Round 17
// 555.986 us; speedup vs baseline: 1.1242x; 1.1242x over previous
//
#include <hip/hip_runtime.h>
#include <cstdint>
#include <cstddef>

#define DM   2048   // D_MODEL
#define DI   4096   // D_INNER
#define DST  16     // D_STATE
#define DTR  128    // DT_RANK
#define SEQL 2048
#define NTOK 4096   // B_SZ * SEQ
#define XZW  8192   // 2*D_INNER
#define NCHAIN 8192 // B_SZ * D_INNER
#define CL   32     // scan chunk length
#define NCH  64     // number of chunks (SEQL / CL)

typedef short short8 __attribute__((ext_vector_type(8)));
typedef float f32x4 __attribute__((ext_vector_type(4)));

__device__ __forceinline__ short f2bf(float x) {
  union { float f; uint32_t u; } v; v.f = x;
  uint32_t r = v.u + 0x7fffu + ((v.u >> 16) & 1u);
  return (short)(r >> 16);
}
__device__ __forceinline__ float bf2f(short s) {
  union { uint32_t u; float f; } v; v.u = ((uint32_t)(uint16_t)s) << 16;
  return v.f;
}

__device__ __forceinline__ void stage16(const short* g, short* l) {
#if __has_builtin(__builtin_amdgcn_global_load_lds)
  __builtin_amdgcn_global_load_lds((const __attribute__((address_space(1))) void*)g,
                                   (__attribute__((address_space(3))) void*)l, 16, 0, 0);
#else
  *(short8*)l = *(const short8*)g;
#endif
}

// ---- fused prep: weight conversions (win,wout,wdt,xp-pad) + RMSNorm ----
#define NG_WIN  (XZW * DM / 4)
#define NG_WOUT (DM * DI / 4)
#define NG_WDT  (DI * DTR / 4)
#define NG_PAD  (256 * DI / 4)
#define NG_ALL  (NG_WIN + NG_WOUT + NG_WDT + NG_PAD)
#define NB_CVT  (NG_ALL / 256)           // 26112 blocks
__global__ __launch_bounds__(256) void prep_k(const float* __restrict__ win,
                                              const float* __restrict__ wout,
                                              const float* __restrict__ wdt,
                                              const float* __restrict__ xp,
                                              const float* __restrict__ hs,
                                              const float* __restrict__ nsc,
                                              short* __restrict__ win_bf,
                                              short* __restrict__ wout_bf,
                                              short* __restrict__ wdt_bf,
                                              short* __restrict__ wxp_bf,
                                              short* __restrict__ xn_bf) {
  const int blk = blockIdx.x;
  const int tid = threadIdx.x;
  if (blk < NB_CVT) {
    const size_t i = (size_t)blk * 256 + tid;
    float4 v;
    short4* dst;
    if (i < NG_WIN) {
      v = ((const float4*)win)[i];
      dst = (short4*)win_bf + i;
    } else if (i < NG_WIN + NG_WOUT) {
      const size_t j = i - NG_WIN;
      v = ((const float4*)wout)[j];
      dst = (short4*)wout_bf + j;
    } else if (i < NG_WIN + NG_WOUT + NG_WDT) {
      const size_t j = i - NG_WIN - NG_WOUT;
      v = ((const float4*)wdt)[j];
      dst = (short4*)wdt_bf + j;
    } else {
      const size_t j = i - NG_WIN - NG_WOUT - NG_WDT;
      const int r = (int)(j >> 10);
      v = (r < 160) ? ((const float4*)xp)[j] : make_float4(0.f, 0.f, 0.f, 0.f);
      dst = (short4*)wxp_bf + j;
    }
    short4 o;
    o.x = f2bf(v.x); o.y = f2bf(v.y); o.z = f2bf(v.z); o.w = f2bf(v.w);
    *dst = o;
  } else {
    const int token = blk - NB_CVT;
    const float* row = hs + (size_t)token * DM;
    float4 a = ((const float4*)row)[tid];
    float4 b = ((const float4*)row)[tid + 256];
    float ss = a.x*a.x + a.y*a.y + a.z*a.z + a.w*a.w
             + b.x*b.x + b.y*b.y + b.z*b.z + b.w*b.w;
    #pragma unroll
    for (int o = 32; o > 0; o >>= 1) ss += __shfl_xor(ss, o);
    __shared__ float wsum[4];
    if ((tid & 63) == 0) wsum[tid >> 6] = ss;
    __syncthreads();
    float tot = wsum[0] + wsum[1] + wsum[2] + wsum[3];
    float inv = rsqrtf(tot * (1.0f / DM) + 1e-5f);
    float4 s1 = ((const float4*)nsc)[tid];
    float4 s2 = ((const float4*)nsc)[tid + 256];
    short4 o1, o2;
    o1.x = f2bf(a.x * inv * s1.x); o1.y = f2bf(a.y * inv * s1.y);
    o1.z = f2bf(a.z * inv * s1.z); o1.w = f2bf(a.w * inv * s1.w);
    o2.x = f2bf(b.x * inv * s2.x); o2.y = f2bf(b.y * inv * s2.y);
    o2.z = f2bf(b.z * inv * s2.z); o2.w = f2bf(b.w * inv * s2.w);
    ((short4*)xn_bf)[(size_t)token * (DM / 4) + tid] = o1;
    ((short4*)xn_bf)[(size_t)token * (DM / 4) + tid + 256] = o2;
  }
}

// ======== 256x256 MFMA GEMM, R12 4-phase + cross-tile PRE schedule, NT ========
// C[m][n] = sum_k A[m][k]*B[n][k].  A: M x K bf16, B: N x K bf16, row-major.
// BM=BN=256, BK=64, 512 threads (2x4 waves). LDS XOR swizzle both-sides.
// Split-K via blockIdx.y. EPI: 0 = f32 store; 1 = softplus(v+aux[col]) -> bf16.
#define LGKM_FENCE() do { asm volatile("s_waitcnt lgkmcnt(0)" ::: "memory"); \
                          __builtin_amdgcn_sched_barrier(0); } while (0)

template <int RBY, int RBX, int EPI>
__global__ __launch_bounds__(512) void gemm_big(const short* __restrict__ A,
                                                const short* __restrict__ B,
                                                int K, int ksz, int N, int nbx,
                                                float* __restrict__ out_f,
                                                size_t zstride,
                                                const float* __restrict__ aux,
                                                short* __restrict__ out_bf) {
  constexpr int MFR = 8;
  constexpr int BM = 256;
  constexpr int ABYTES = BM * 128;       // 32 KB
  constexpr int BBYTES = 256 * 128;      // 32 KB
  constexpr int BUF = ABYTES + BBYTES;
  constexpr int FPP = 4;
  __shared__ char lds[2 * BUF];

  const int tid = threadIdx.x;
  const int lane = tid & 63;
  const int wid = tid >> 6;
  const int wm = wid >> 2;      // 0..1
  const int wn = wid & 3;       // 0..3
  const int lr = lane & 15;
  const int lj = lane >> 4;

  // XCD square-region mapping
  const int xcd = blockIdx.x & 7;
  const int idx = blockIdx.x >> 3;
  const int nrgx = nbx / RBX;
  const int by = (xcd / nrgx) * RBY + idx / RBX;
  const int bx = (xcd % nrgx) * RBX + idx % RBX;
  const size_t m0 = (size_t)by * BM;
  const size_t n0 = (size_t)bx * 256;

  const int kbase = blockIdx.y * ksz;
  out_f += (size_t)blockIdx.y * zstride;
  const int NT = ksz >> 6;

  auto stA1 = [&](int t, char* buf, int s) {
    const int k0 = kbase + (t << 6);
    const int off = s * 8192 + tid * 16;
    const int r = off >> 7;
    const int j = (off >> 4) & 7;
    stage16(A + (m0 + r) * (size_t)K + k0 + ((j ^ (r & 7)) << 3),
            (short*)(buf + off));
  };
  auto stB1 = [&](int t, char* buf, int s) {
    const int k0 = kbase + (t << 6);
    const int off = s * 8192 + tid * 16;
    const int r = off >> 7;
    const int j = (off >> 4) & 7;
    stage16(B + (n0 + r) * (size_t)K + k0 + ((j ^ (r & 7)) << 3),
            (short*)(buf + ABYTES + off));
  };

#define READ_A(dst, fbase)                                                   \
  _Pragma("unroll")                                                          \
  for (int f = 0; f < 4; ++f) {                                              \
    const int arow = wm * (BM / 2) + ((fbase) + f) * 16 + lr;                \
    _Pragma("unroll")                                                        \
    for (int ks = 0; ks < 2; ++ks)                                           \
      dst[f][ks] = *(const short8*)(cur + arow * 128 +                       \
                     ((((ks << 2) + lj) ^ (arow & 7)) << 4));                \
  }
#define READ_B(dst, gbase)                                                   \
  _Pragma("unroll")                                                          \
  for (int g = 0; g < 2; ++g) {                                              \
    const int brow = wn * 64 + ((gbase) + g) * 16 + lr;                      \
    _Pragma("unroll")                                                        \
    for (int ks = 0; ks < 2; ++ks)                                           \
      dst[g][ks] = *(const short8*)(cur + ABYTES + brow * 128 +              \
                     ((((ks << 2) + lj) ^ (brow & 7)) << 4));                \
  }
#define MFMA_Q(accoff, avoff, gbase, bvx)                                    \
  __builtin_amdgcn_s_setprio(1);                                             \
  _Pragma("unroll")                                                          \
  for (int ks = 0; ks < 2; ++ks)                                             \
    _Pragma("unroll")                                                        \
    for (int f = 0; f < FPP; ++f)                                            \
      _Pragma("unroll")                                                      \
      for (int g = 0; g < 2; ++g)                                            \
        acc[(accoff) + f][(gbase) + g] = __builtin_amdgcn_mfma_f32_16x16x32_bf16( \
            av[(avoff) + f][ks], bvx[g][ks], acc[(accoff) + f][(gbase) + g], 0, 0, 0); \
  __builtin_amdgcn_s_setprio(0);

  f32x4 acc[MFR][4] = {};

  // prologue: tile 0 fully; pre-issue tile 1's A-lo regions
  {
    #pragma unroll
    for (int s = 0; s < 4; ++s) stA1(0, lds, s);
    #pragma unroll
    for (int s = 0; s < 4; ++s) stB1(0, lds, s);
    if (NT > 1) {
      stA1(1, lds + BUF, 0); stA1(1, lds + BUF, 2);
      asm volatile("s_waitcnt vmcnt(2)" ::: "memory");
    } else asm volatile("s_waitcnt vmcnt(0)" ::: "memory");
    __builtin_amdgcn_s_barrier();
    __builtin_amdgcn_sched_barrier(0);
  }

  for (int t = 0; t < NT; ++t) {
    char* cur = lds + (t & 1) * BUF;
    char* nxt = lds + ((t + 1) & 1) * BUF;
    const bool m1 = (t + 1) < NT;
    const bool m2 = (t + 2) < NT;
    short8 av[4][2], bv0[2][2], bv1[2][2];

    // ---- phase 0: read A0 + B0; stage A(t+1) hi regions
    READ_A(av, 0);
    READ_B(bv0, 0);
    if (m1) { stA1(t + 1, nxt, 1); stA1(t + 1, nxt, 3); }
    LGKM_FENCE();
    MFMA_Q(0, 0, 0, bv0);
    __builtin_amdgcn_s_barrier();

    // ---- phase 1: read B1; stage B_lo(t+1)
    READ_B(bv1, 2);
    if (m1) { stB1(t + 1, nxt, 0); stB1(t + 1, nxt, 1); }
    LGKM_FENCE();
    MFMA_Q(0, 0, 2, bv1);
    __builtin_amdgcn_s_barrier();

    // ---- phase 2: read A1; stage B_hi(t+1); pre-issue A_lo(t+2) into cur
    READ_A(av, 4);
    if (m1) { stB1(t + 1, nxt, 2); stB1(t + 1, nxt, 3); }
    if (m2) { stA1(t + 2, cur, 0); stA1(t + 2, cur, 2); }
    LGKM_FENCE();
    MFMA_Q(4, 0, 2, bv1);
    __builtin_amdgcn_s_barrier();

    // ---- phase 3: MFMA A1 x B0 (reg-cached); publish with counted vmcnt
    MFMA_Q(4, 0, 0, bv0);
    if (m2) asm volatile("s_waitcnt vmcnt(2)" ::: "memory");
    else    asm volatile("s_waitcnt vmcnt(0)" ::: "memory");
    __builtin_amdgcn_s_barrier();
    __builtin_amdgcn_sched_barrier(0);
  }

  #pragma unroll
  for (int f = 0; f < MFR; ++f)
    #pragma unroll
    for (int g = 0; g < 4; ++g)
      #pragma unroll
      for (int jj = 0; jj < 4; ++jj) {
        const size_t row = m0 + wm * (BM / 2) + f * 16 + lj * 4 + jj;
        const size_t col = n0 + wn * 64 + g * 16 + lr;
        if constexpr (EPI == 0) {
          out_f[row * (size_t)N + col] = acc[f][g][jj];
        } else {
          float x = acc[f][g][jj] + aux[col];
          float sp = (x > 20.f) ? x : log1pf(__expf(x));
          out_bf[row * (size_t)N + col] = f2bf(sp);
        }
      }
#undef READ_A
#undef READ_B
#undef MFMA_Q
}

// ---- out_proj combine: out0 = residual + partial0 + partial1 ----
__global__ __launch_bounds__(256) void combine_k(const float* __restrict__ part,
                                                 const float* __restrict__ hs,
                                                 float* __restrict__ out0) {
  const size_t i = (size_t)blockIdx.x * 256 + threadIdx.x;   // float4 index
  const float4 p0 = ((const float4*)part)[i];
  const float4 p1 = ((const float4*)part)[i + (size_t)NTOK * DM / 4];
  const float4 r  = ((const float4*)hs)[i];
  float4 o;
  o.x = r.x + p0.x + p1.x; o.y = r.y + p0.y + p1.y;
  o.z = r.z + p0.z + p1.z; o.w = r.w + p0.w + p1.w;
  ((float4*)out0)[i] = o;
}

// ---------------- small NT bf16 MFMA GEMM, 128x128x64 tile ----------------
// EPI 4: store f32 partial at out_f[(z*NTOK + row)*N + col], col<160 only
__global__ __launch_bounds__(256) void gemm_nt4(const short* __restrict__ A,
                                                const short* __restrict__ B,
                                                int ld, int K, int N,
                                                float* __restrict__ out_f) {
  __shared__ short As[128 * 64];
  __shared__ short Bs[128 * 64];
  const int tid = threadIdx.x;
  const int lane = tid & 63;
  const int wid = tid >> 6;
  const int wr = wid >> 1, wc = wid & 1;
  const size_t m0 = (size_t)blockIdx.y * 128;
  const size_t n0 = (size_t)blockIdx.x * 128;
  A += (size_t)blockIdx.z * K;
  B += (size_t)blockIdx.z * K;
  f32x4 acc[4][4] = {};
  for (int k0 = 0; k0 < K; k0 += 64) {
    #pragma unroll
    for (int i = 0; i < 4; ++i) {
      const int off = i * 4096 + tid * 16;   // byte offset in 16KB tile
      const int r = off >> 7;                // tile row (128B per row)
      const int ke = (off & 127) >> 1;       // element offset in row
      stage16(A + (m0 + r) * (size_t)ld + k0 + ke, &As[off >> 1]);
      stage16(B + (n0 + r) * (size_t)ld + k0 + ke, &Bs[off >> 1]);
    }
    __syncthreads();
    #pragma unroll
    for (int kk = 0; kk < 64; kk += 32) {
      short8 af[4], bfr[4];
      const int kb = kk + (lane >> 4) * 8;
      const int rr = lane & 15;
      #pragma unroll
      for (int f = 0; f < 4; ++f) {
        af[f]  = *(const short8*)&As[(wr * 64 + f * 16 + rr) * 64 + kb];
        bfr[f] = *(const short8*)&Bs[(wc * 64 + f * 16 + rr) * 64 + kb];
      }
      #pragma unroll
      for (int fm = 0; fm < 4; ++fm)
        #pragma unroll
        for (int fn = 0; fn < 4; ++fn)
          acc[fm][fn] = __builtin_amdgcn_mfma_f32_16x16x32_bf16(af[fm], bfr[fn], acc[fm][fn], 0, 0, 0);
    }
    __syncthreads();
  }
  const int rbase = (lane >> 4) * 4;
  const int cbase = lane & 15;
  #pragma unroll
  for (int fm = 0; fm < 4; ++fm) {
    #pragma unroll
    for (int fn = 0; fn < 4; ++fn) {
      #pragma unroll
      for (int j = 0; j < 4; ++j) {
        const size_t row = m0 + wr * 64 + fm * 16 + rbase + j;
        const size_t col = n0 + wc * 64 + fn * 16 + cbase;
        if (col < 160)
          out_f[((size_t)blockIdx.z * NTOK + row) * (size_t)N + col] = acc[fm][fn][j];
      }
    }
  }
}

// ---- x_dbl epilogue: sum 4 split-K partials, split into dt_low/B/C ----
__global__ __launch_bounds__(256) void xdbl_epi_k(const float* __restrict__ part,
                                                  short* __restrict__ dtl,
                                                  float* __restrict__ Bc,
                                                  float* __restrict__ Cc) {
  const int row = blockIdx.x;
  const int col = threadIdx.x;
  if (col >= 160) return;
  const size_t i = (size_t)row * 256 + col;
  const float v = part[i] + part[(size_t)NTOK * 256 + i]
                + part[(size_t)2 * NTOK * 256 + i]
                + part[(size_t)3 * NTOK * 256 + i];
  if (col < 128)      dtl[(size_t)row * 128 + col] = f2bf(v);
  else if (col < 144) Bc[(size_t)row * 16 + (col - 128)] = v;
  else                Cc[(size_t)row * 16 + (col - 144)] = v;
}

// ------- causal depthwise conv (W=4) + SiLU, rolling window, 8 tok/thread -------
__global__ __launch_bounds__(256) void conv_silu_k(const float* __restrict__ xz,
                                                   const float* __restrict__ cw,
                                                   const float* __restrict__ cb,
                                                   short* __restrict__ xc) {
  const int d = blockIdx.x * 256 + threadIdx.x;
  const int t0 = blockIdx.y * 8;          // global token base (never crosses seq)
  const int l0 = t0 & (SEQL - 1);         // within-sequence index
  const float4 w = ((const float4*)cw)[d];
  const float bias = cb[d];
  float x0 = (l0 >= 3) ? xz[(size_t)(t0 - 3) * XZW + d] : 0.f;
  float x1 = (l0 >= 2) ? xz[(size_t)(t0 - 2) * XZW + d] : 0.f;
  float x2 = (l0 >= 1) ? xz[(size_t)(t0 - 1) * XZW + d] : 0.f;
  #pragma unroll
  for (int i = 0; i < 8; ++i) {
    const float x3 = xz[(size_t)(t0 + i) * XZW + d];
    const float acc = bias + w.x * x0 + w.y * x1 + w.z * x2 + w.w * x3;
    const float sv = acc / (1.f + __expf(-acc));
    xc[(size_t)(t0 + i) * DI + d] = f2bf(sv);
    x0 = x1; x1 = x2; x2 = x3;
  }
}

// ---------------- chunked selective scan (2 threads/chain, 8 states each) ----------------
// t = ((chunk*NCHAIN + chain) * 2 + sub); sub in {0,1} owns states 8*sub..8*sub+7
__global__ __launch_bounds__(256) void scan1_k(const short* __restrict__ del_bf,
                                               const short* __restrict__ xc,
                                               const float* __restrict__ Bc,
                                               const float* __restrict__ alog,
                                               float* __restrict__ hloc,
                                               float* __restrict__ Ssum) {
  const int t = blockIdx.x * 256 + threadIdx.x;   // 1,048,576 threads
  const int sub = t & 1;
  const int chain = (t >> 1) & (NCHAIN - 1);      // (b,d)
  const int chunk = t >> 14;
  const int b = chain >> 12;
  const int d = chain & 4095;
  float A[8];
  #pragma unroll
  for (int j = 0; j < 8; ++j) A[j] = -__expf(alog[d * 16 + sub * 8 + j]);
  float h[8] = {};
  float S = 0.f;
  size_t token = (size_t)b * SEQL + (size_t)chunk * CL;
  #pragma unroll 2
  for (int l = 0; l < CL; ++l, ++token) {
    const float delta = bf2f(del_bf[token * DI + d]);
    const float u = bf2f(xc[token * DI + d]);
    const float du = delta * u;
    S += delta;
    const float4 B0 = ((const float4*)Bc)[token * 4 + sub * 2];
    const float4 B1 = ((const float4*)Bc)[token * 4 + sub * 2 + 1];
    const float Bv[8] = {B0.x, B0.y, B0.z, B0.w, B1.x, B1.y, B1.z, B1.w};
    #pragma unroll
    for (int j = 0; j < 8; ++j)
      h[j] = h[j] * __expf(delta * A[j]) + du * Bv[j];
  }
  const size_t idx = (size_t)(chunk * NCHAIN + chain) * 4 + sub * 2;
  ((float4*)hloc)[idx]     = make_float4(h[0], h[1], h[2], h[3]);
  ((float4*)hloc)[idx + 1] = make_float4(h[4], h[5], h[6], h[7]);
  if (sub == 0) Ssum[chunk * NCHAIN + chain] = S;
}

// pass 2: serial combine over chunks, IN-PLACE (hloc[c] becomes h_in[c])
__global__ __launch_bounds__(256) void scan2_k(float* __restrict__ hloc,
                                               const float* __restrict__ Ssum,
                                               const float* __restrict__ alog) {
  const int t = blockIdx.x * 256 + threadIdx.x;   // 32768 threads
  const int q = t & 3;
  const int chain = t >> 2;
  const int d = chain & 4095;
  float A[4];
  #pragma unroll
  for (int j = 0; j < 4; ++j) A[j] = -__expf(alog[d * 16 + q * 4 + j]);
  float4 h = make_float4(0.f, 0.f, 0.f, 0.f);
  for (int c = 0; c < NCH; ++c) {
    const size_t idx = (size_t)(c * NCHAIN + chain) * 4 + q;
    const float S = Ssum[c * NCHAIN + chain];
    const float4 hl = ((const float4*)hloc)[idx];
    ((float4*)hloc)[idx] = h;                 // publish prefix state
    h.x = h.x * __expf(A[0] * S) + hl.x;
    h.y = h.y * __expf(A[1] * S) + hl.y;
    h.z = h.z * __expf(A[2] * S) + hl.z;
    h.w = h.w * __expf(A[3] * S) + hl.w;
  }
}

// pass 3: re-scan chunk from h_in (stored in hloc), y + D-skip + z-gate -> y bf16
__global__ __launch_bounds__(256) void scan3_k(const short* __restrict__ del_bf,
                                               const short* __restrict__ xc,
                                               const float* __restrict__ Bc,
                                               const float* __restrict__ Cc,
                                               const float* __restrict__ xzbuf,
                                               const float* __restrict__ alog,
                                               const float* __restrict__ dvec,
                                               const float* __restrict__ hin,
                                               short* __restrict__ y) {
  const int t = blockIdx.x * 256 + threadIdx.x;
  const int sub = t & 1;
  const int chain = (t >> 1) & (NCHAIN - 1);
  const int chunk = t >> 14;
  const int b = chain >> 12;
  const int d = chain & 4095;
  float A[8];
  #pragma unroll
  for (int j = 0; j < 8; ++j) A[j] = -__expf(alog[d * 16 + sub * 8 + j]);
  const float Dd = dvec[d];
  const size_t idx = (size_t)(chunk * NCHAIN + chain) * 4 + sub * 2;
  const float4 h0 = ((const float4*)hin)[idx];
  const float4 h1 = ((const float4*)hin)[idx + 1];
  float h[8] = {h0.x, h0.y, h0.z, h0.w, h1.x, h1.y, h1.z, h1.w};
  size_t token = (size_t)b * SEQL + (size_t)chunk * CL;
  #pragma unroll 2
  for (int l = 0; l < CL; ++l, ++token) {
    const float delta = bf2f(del_bf[token * DI + d]);
    const float u = bf2f(xc[token * DI + d]);
    const float du = delta * u;
    const float4 B0 = ((const float4*)Bc)[token * 4 + sub * 2];
    const float4 B1 = ((const float4*)Bc)[token * 4 + sub * 2 + 1];
    const float4 C0 = ((const float4*)Cc)[token * 4 + sub * 2];
    const float4 C1 = ((const float4*)Cc)[token * 4 + sub * 2 + 1];
    const float Bv[8] = {B0.x, B0.y, B0.z, B0.w, B1.x, B1.y, B1.z, B1.w};
    const float Cv[8] = {C0.x, C0.y, C0.z, C0.w, C1.x, C1.y, C1.z, C1.w};
    float yp = 0.f;
    #pragma unroll
    for (int j = 0; j < 8; ++j) {
      h[j] = h[j] * __expf(delta * A[j]) + du * Bv[j];
      yp += h[j] * Cv[j];
    }
    yp += __shfl_xor(yp, 1);
    if (sub == 0) {
      const float z = xzbuf[token * XZW + DI + d];
      const float sz = z / (1.f + __expf(-z));
      y[token * DI + d] = f2bf((yp + u * Dd) * sz);
    }
  }
}

extern "C" void kernel_launch(void* const* d_in, const int* in_sizes, int n_in,
                              void* d_out, int out_size, void* d_ws, size_t ws_size,
                              hipStream_t stream) {
  const float* hs   = (const float*)d_in[0];   // (B,L,2048)
  const float* nsc  = (const float*)d_in[1];
  const float* win  = (const float*)d_in[2];   // (8192,2048)
  const float* cw   = (const float*)d_in[3];   // (4096,1,4)
  const float* cb   = (const float*)d_in[4];
  const float* wxp  = (const float*)d_in[5];   // (160,4096)
  const float* wdt  = (const float*)d_in[6];   // (4096,128)
  const float* bdt  = (const float*)d_in[7];
  const float* wout = (const float*)d_in[8];   // (2048,4096)
  const float* alog = (const float*)d_in[9];   // (4096,16)
  const float* dvec = (const float*)d_in[10];

  float* out0 = (float*)d_out;                       // (4096, 2048)
  float* xz   = out0 + (size_t)NTOK * DM;            // (4096, 8192)

  char* w = (char*)d_ws;
  size_t off = 0;
  auto alloc = [&](size_t bytes) {
    char* p = w + off;
    off += (bytes + 255) & ~(size_t)255;
    return p;
  };
  short* xn_bf   = (short*)alloc((size_t)NTOK * DM * 2);      // dead after gemm_big(in_proj)
  short* win_bf  = (short*)alloc((size_t)XZW * DM * 2);       // dead after gemm_big(in_proj)
  short* wout_bf = (short*)alloc((size_t)DM * DI * 2);
  short* wdt_bf  = (short*)alloc((size_t)DI * DTR * 2);
  short* wxp_bf  = (short*)alloc((size_t)256 * DI * 2);
  short* xc_bf   = (short*)alloc((size_t)NTOK * DI * 2);      // dead after scan3
  short* dtl_bf  = (short*)alloc((size_t)NTOK * DTR * 2);     // dead after dt_proj
  float* Bc      = (float*)alloc((size_t)NTOK * DST * 4);     // dead after scan3
  float* Cc      = (float*)alloc((size_t)NTOK * DST * 4);     // dead after scan3
  short* del_bf  = (short*)alloc((size_t)NTOK * DI * 2);      // dead after scan3
  short* y_bf    = (short*)alloc((size_t)NTOK * DI * 2);

  // Aliased scratch (lifetimes disjoint within one call):
  float* xp_part = (float*)win_bf;
  float* hloc    = (float*)win_bf;
  float* Ssum    = (float*)xn_bf;
  float* opart   = (float*)xc_bf;

  // 0+1. fused weight conversions + RMSNorm
  prep_k<<<NB_CVT + NTOK, 256, 0, stream>>>(
      win, wout, wdt, wxp, hs, nsc, win_bf, wout_bf, wdt_bf, wxp_bf, xn_bf);
  // 2. xz = xn @ in_proj^T  -> d_out (output 1)
  gemm_big<8, 8, 0><<<dim3((XZW / 256) * (NTOK / 256)), 512, 0, stream>>>(
      xn_bf, win_bf, DM, DM, XZW, XZW / 256, xz, 0, nullptr, nullptr);
  // 3. causal depthwise conv + SiLU
  conv_silu_k<<<dim3(DI / 256, NTOK / 8), 256, 0, stream>>>(xz, cw, cb, xc_bf);
  // 4. x_dbl = xc @ x_proj^T, split-K x4 -> partials (160 cols) -> dt_low/B/C
  gemm_nt4<<<dim3(2, NTOK / 128, 4), 256, 0, stream>>>(
      xc_bf, wxp_bf, DI, DI / 4, 256, xp_part);
  xdbl_epi_k<<<NTOK, 256, 0, stream>>>(xp_part, dtl_bf, Bc, Cc);
  // 5. delta = softplus(dt_low @ dt_proj^T + b) -> bf16  [256x256 schedule]
  gemm_big<8, 4, 1><<<dim3((DI / 256) * (NTOK / 256)), 512, 0, stream>>>(
      dtl_bf, wdt_bf, DTR, DTR, DI, DI / 256, nullptr, 0, bdt, del_bf);
  // 6. chunked selective scan + gating -> y bf16  (2 threads/chain, CL=32)
  scan1_k<<<(NCHAIN * 2 * NCH) / 256, 256, 0, stream>>>(
      del_bf, xc_bf, Bc, alog, hloc, Ssum);
  scan2_k<<<(NCHAIN * 4) / 256, 256, 0, stream>>>(hloc, Ssum, alog);
  scan3_k<<<(NCHAIN * 2 * NCH) / 256, 256, 0, stream>>>(
      del_bf, xc_bf, Bc, Cc, xz, alog, dvec, hloc, y_bf);
  // 7. out_proj via split-K=2: 128 tiles x 2 K-halves = 256 blocks
  gemm_big<4, 4, 0><<<dim3((DM / 256) * (NTOK / 256), 2), 512, 0, stream>>>(
      y_bf, wout_bf, DI, DI / 2, DM, DM / 256, opart, (size_t)NTOK * DM,
      nullptr, nullptr);
  combine_k<<<(NTOK * DM / 4) / 256, 256, 0, stream>>>(opart, hs, out0);
}

// Round 18
// 544.933 us; speedup vs baseline: 1.1470x; 1.0203x over previous
//
#include <hip/hip_runtime.h>
#include <cstdint>
#include <cstddef>

#define DM   2048   // D_MODEL
#define DI   4096   // D_INNER
#define DST  16     // D_STATE
#define DTR  128    // DT_RANK
#define SEQL 2048
#define NTOK 4096   // B_SZ * SEQ
#define XZW  8192   // 2*D_INNER
#define NCHAIN 8192 // B_SZ * D_INNER
#define CL   32     // scan chunk length
#define NCH  64     // number of chunks (SEQL / CL)

typedef short short8 __attribute__((ext_vector_type(8)));
typedef float f32x4 __attribute__((ext_vector_type(4)));

__device__ __forceinline__ short f2bf(float x) {
  union { float f; uint32_t u; } v; v.f = x;
  uint32_t r = v.u + 0x7fffu + ((v.u >> 16) & 1u);
  return (short)(r >> 16);
}
__device__ __forceinline__ float bf2f(short s) {
  union { uint32_t u; float f; } v; v.u = ((uint32_t)(uint16_t)s) << 16;
  return v.f;
}

__device__ __forceinline__ void stage16(const short* g, short* l) {
#if __has_builtin(__builtin_amdgcn_global_load_lds)
  __builtin_amdgcn_global_load_lds((const __attribute__((address_space(1))) void*)g,
                                   (__attribute__((address_space(3))) void*)l, 16, 0, 0);
#else
  *(short8*)l = *(const short8*)g;
#endif
}

// ---- fused prep: weight conversions (win,wout,wdt,xp-pad) + RMSNorm ----
#define NG_WIN  (XZW * DM / 4)
#define NG_WOUT (DM * DI / 4)
#define NG_WDT  (DI * DTR / 4)
#define NG_PAD  (256 * DI / 4)
#define NG_ALL  (NG_WIN + NG_WOUT + NG_WDT + NG_PAD)
#define NB_CVT  (NG_ALL / 256)           // 26112 blocks
__global__ __launch_bounds__(256) void prep_k(const float* __restrict__ win,
                                              const float* __restrict__ wout,
                                              const float* __restrict__ wdt,
                                              const float* __restrict__ xp,
                                              const float* __restrict__ hs,
                                              const float* __restrict__ nsc,
                                              short* __restrict__ win_bf,
                                              short* __restrict__ wout_bf,
                                              short* __restrict__ wdt_bf,
                                              short* __restrict__ wxp_bf,
                                              short* __restrict__ xn_bf) {
  const int blk = blockIdx.x;
  const int tid = threadIdx.x;
  if (blk < NB_CVT) {
    const size_t i = (size_t)blk * 256 + tid;
    float4 v;
    short4* dst;
    if (i < NG_WIN) {
      v = ((const float4*)win)[i];
      dst = (short4*)win_bf + i;
    } else if (i < NG_WIN + NG_WOUT) {
      const size_t j = i - NG_WIN;
      v = ((const float4*)wout)[j];
      dst = (short4*)wout_bf + j;
    } else if (i < NG_WIN + NG_WOUT + NG_WDT) {
      const size_t j = i - NG_WIN - NG_WOUT;
      v = ((const float4*)wdt)[j];
      dst = (short4*)wdt_bf + j;
    } else {
      const size_t j = i - NG_WIN - NG_WOUT - NG_WDT;
      const int r = (int)(j >> 10);
      v = (r < 160) ? ((const float4*)xp)[j] : make_float4(0.f, 0.f, 0.f, 0.f);
      dst = (short4*)wxp_bf + j;
    }
    short4 o;
    o.x = f2bf(v.x); o.y = f2bf(v.y); o.z = f2bf(v.z); o.w = f2bf(v.w);
    *dst = o;
  } else {
    const int token = blk - NB_CVT;
    const float* row = hs + (size_t)token * DM;
    float4 a = ((const float4*)row)[tid];
    float4 b = ((const float4*)row)[tid + 256];
    float ss = a.x*a.x + a.y*a.y + a.z*a.z + a.w*a.w
             + b.x*b.x + b.y*b.y + b.z*b.z + b.w*b.w;
    #pragma unroll
    for (int o = 32; o > 0; o >>= 1) ss += __shfl_xor(ss, o);
    __shared__ float wsum[4];
    if ((tid & 63) == 0) wsum[tid >> 6] = ss;
    __syncthreads();
    float tot = wsum[0] + wsum[1] + wsum[2] + wsum[3];
    float inv = rsqrtf(tot * (1.0f / DM) + 1e-5f);
    float4 s1 = ((const float4*)nsc)[tid];
    float4 s2 = ((const float4*)nsc)[tid + 256];
    short4 o1, o2;
    o1.x = f2bf(a.x * inv * s1.x); o1.y = f2bf(a.y * inv * s1.y);
    o1.z = f2bf(a.z * inv * s1.z); o1.w = f2bf(a.w * inv * s1.w);
    o2.x = f2bf(b.x * inv * s2.x); o2.y = f2bf(b.y * inv * s2.y);
    o2.z = f2bf(b.z * inv * s2.z); o2.w = f2bf(b.w * inv * s2.w);
    ((short4*)xn_bf)[(size_t)token * (DM / 4) + tid] = o1;
    ((short4*)xn_bf)[(size_t)token * (DM / 4) + tid + 256] = o2;
  }
}

// ======== 256x256 MFMA GEMM, R12 4-phase + cross-tile PRE schedule, NT ========
// C[m][n] = sum_k A[m][k]*B[n][k].  A: M x K bf16, B: N x K bf16, row-major.
// BM=BN=256, BK=64, 512 threads (2x4 waves). LDS XOR swizzle both-sides.
// Split-K via blockIdx.y (out_bf partials for EPI=2).
// EPI: 0 = f32 store; 1 = softplus(v+aux[col]) -> bf16; 2 = bf16 store.
#define LGKM_FENCE() do { asm volatile("s_waitcnt lgkmcnt(0)" ::: "memory"); \
                          __builtin_amdgcn_sched_barrier(0); } while (0)

template <int RBY, int RBX, int EPI>
__global__ __launch_bounds__(512) void gemm_big(const short* __restrict__ A,
                                                const short* __restrict__ B,
                                                int K, int ksz, int N, int nbx,
                                                float* __restrict__ out_f,
                                                size_t zstride,
                                                const float* __restrict__ aux,
                                                short* __restrict__ out_bf) {
  constexpr int MFR = 8;
  constexpr int BM = 256;
  constexpr int ABYTES = BM * 128;       // 32 KB
  constexpr int BBYTES = 256 * 128;      // 32 KB
  constexpr int BUF = ABYTES + BBYTES;
  constexpr int FPP = 4;
  __shared__ char lds[2 * BUF];

  const int tid = threadIdx.x;
  const int lane = tid & 63;
  const int wid = tid >> 6;
  const int wm = wid >> 2;      // 0..1
  const int wn = wid & 3;       // 0..3
  const int lr = lane & 15;
  const int lj = lane >> 4;

  // XCD square-region mapping
  const int xcd = blockIdx.x & 7;
  const int idx = blockIdx.x >> 3;
  const int nrgx = nbx / RBX;
  const int by = (xcd / nrgx) * RBY + idx / RBX;
  const int bx = (xcd % nrgx) * RBX + idx % RBX;
  const size_t m0 = (size_t)by * BM;
  const size_t n0 = (size_t)bx * 256;

  const int kbase = blockIdx.y * ksz;
  out_f += (size_t)blockIdx.y * zstride;
  out_bf += (size_t)blockIdx.y * zstride;
  const int NT = ksz >> 6;

  auto stA1 = [&](int t, char* buf, int s) {
    const int k0 = kbase + (t << 6);
    const int off = s * 8192 + tid * 16;
    const int r = off >> 7;
    const int j = (off >> 4) & 7;
    stage16(A + (m0 + r) * (size_t)K + k0 + ((j ^ (r & 7)) << 3),
            (short*)(buf + off));
  };
  auto stB1 = [&](int t, char* buf, int s) {
    const int k0 = kbase + (t << 6);
    const int off = s * 8192 + tid * 16;
    const int r = off >> 7;
    const int j = (off >> 4) & 7;
    stage16(B + (n0 + r) * (size_t)K + k0 + ((j ^ (r & 7)) << 3),
            (short*)(buf + ABYTES + off));
  };

#define READ_A(dst, fbase)                                                   \
  _Pragma("unroll")                                                          \
  for (int f = 0; f < 4; ++f) {                                              \
    const int arow = wm * (BM / 2) + ((fbase) + f) * 16 + lr;                \
    _Pragma("unroll")                                                        \
    for (int ks = 0; ks < 2; ++ks)                                           \
      dst[f][ks] = *(const short8*)(cur + arow * 128 +                       \
                     ((((ks << 2) + lj) ^ (arow & 7)) << 4));                \
  }
#define READ_B(dst, gbase)                                                   \
  _Pragma("unroll")                                                          \
  for (int g = 0; g < 2; ++g) {                                              \
    const int brow = wn * 64 + ((gbase) + g) * 16 + lr;                      \
    _Pragma("unroll")                                                        \
    for (int ks = 0; ks < 2; ++ks)                                           \
      dst[g][ks] = *(const short8*)(cur + ABYTES + brow * 128 +              \
                     ((((ks << 2) + lj) ^ (brow & 7)) << 4));                \
  }
#define MFMA_Q(accoff, avoff, gbase, bvx)                                    \
  __builtin_amdgcn_s_setprio(1);                                             \
  _Pragma("unroll")                                                          \
  for (int ks = 0; ks < 2; ++ks)                                             \
    _Pragma("unroll")                                                        \
    for (int f = 0; f < FPP; ++f)                                            \
      _Pragma("unroll")                                                      \
      for (int g = 0; g < 2; ++g)                                            \
        acc[(accoff) + f][(gbase) + g] = __builtin_amdgcn_mfma_f32_16x16x32_bf16( \
            av[(avoff) + f][ks], bvx[g][ks], acc[(accoff) + f][(gbase) + g], 0, 0, 0); \
  __builtin_amdgcn_s_setprio(0);

  f32x4 acc[MFR][4] = {};

  // prologue: tile 0 fully; pre-issue tile 1's A-lo regions
  {
    #pragma unroll
    for (int s = 0; s < 4; ++s) stA1(0, lds, s);
    #pragma unroll
    for (int s = 0; s < 4; ++s) stB1(0, lds, s);
    if (NT > 1) {
      stA1(1, lds + BUF, 0); stA1(1, lds + BUF, 2);
      asm volatile("s_waitcnt vmcnt(2)" ::: "memory");
    } else asm volatile("s_waitcnt vmcnt(0)" ::: "memory");
    __builtin_amdgcn_s_barrier();
    __builtin_amdgcn_sched_barrier(0);
  }

  for (int t = 0; t < NT; ++t) {
    char* cur = lds + (t & 1) * BUF;
    char* nxt = lds + ((t + 1) & 1) * BUF;
    const bool m1 = (t + 1) < NT;
    const bool m2 = (t + 2) < NT;
    short8 av[4][2], bv0[2][2], bv1[2][2];

    // ---- phase 0: read A0 + B0; stage A(t+1) hi regions
    READ_A(av, 0);
    READ_B(bv0, 0);
    if (m1) { stA1(t + 1, nxt, 1); stA1(t + 1, nxt, 3); }
    LGKM_FENCE();
    MFMA_Q(0, 0, 0, bv0);
    __builtin_amdgcn_s_barrier();

    // ---- phase 1: read B1; stage B_lo(t+1)
    READ_B(bv1, 2);
    if (m1) { stB1(t + 1, nxt, 0); stB1(t + 1, nxt, 1); }
    LGKM_FENCE();
    MFMA_Q(0, 0, 2, bv1);
    __builtin_amdgcn_s_barrier();

    // ---- phase 2: read A1; stage B_hi(t+1); pre-issue A_lo(t+2) into cur
    READ_A(av, 4);
    if (m1) { stB1(t + 1, nxt, 2); stB1(t + 1, nxt, 3); }
    if (m2) { stA1(t + 2, cur, 0); stA1(t + 2, cur, 2); }
    LGKM_FENCE();
    MFMA_Q(4, 0, 2, bv1);
    __builtin_amdgcn_s_barrier();

    // ---- phase 3: MFMA A1 x B0 (reg-cached); publish with counted vmcnt
    MFMA_Q(4, 0, 0, bv0);
    if (m2) asm volatile("s_waitcnt vmcnt(2)" ::: "memory");
    else    asm volatile("s_waitcnt vmcnt(0)" ::: "memory");
    __builtin_amdgcn_s_barrier();
    __builtin_amdgcn_sched_barrier(0);
  }

  #pragma unroll
  for (int f = 0; f < MFR; ++f)
    #pragma unroll
    for (int g = 0; g < 4; ++g)
      #pragma unroll
      for (int jj = 0; jj < 4; ++jj) {
        const size_t row = m0 + wm * (BM / 2) + f * 16 + lj * 4 + jj;
        const size_t col = n0 + wn * 64 + g * 16 + lr;
        if constexpr (EPI == 0) {
          out_f[row * (size_t)N + col] = acc[f][g][jj];
        } else if constexpr (EPI == 1) {
          float x = acc[f][g][jj] + aux[col];
          float sp = (x > 20.f) ? x : log1pf(__expf(x));
          out_bf[row * (size_t)N + col] = f2bf(sp);
        } else {
          out_bf[row * (size_t)N + col] = f2bf(acc[f][g][jj]);
        }
      }
#undef READ_A
#undef READ_B
#undef MFMA_Q
}

// ---- out_proj combine: out0 = residual + bf16 partial0 + bf16 partial1 ----
__global__ __launch_bounds__(256) void combine_k(const short* __restrict__ part,
                                                 const float* __restrict__ hs,
                                                 float* __restrict__ out0) {
  const size_t i = (size_t)blockIdx.x * 256 + threadIdx.x;   // float4 index
  const short4 p0 = ((const short4*)part)[i];
  const short4 p1 = ((const short4*)part)[i + (size_t)NTOK * DM / 4];
  const float4 r  = ((const float4*)hs)[i];
  float4 o;
  o.x = r.x + bf2f(p0.x) + bf2f(p1.x);
  o.y = r.y + bf2f(p0.y) + bf2f(p1.y);
  o.z = r.z + bf2f(p0.z) + bf2f(p1.z);
  o.w = r.w + bf2f(p0.w) + bf2f(p1.w);
  ((float4*)out0)[i] = o;
}

// ---------------- small NT bf16 MFMA GEMM, 128x128x64 tile ----------------
// EPI 4: store f32 partial at out_f[(z*NTOK + row)*N + col], col<160 only
__global__ __launch_bounds__(256) void gemm_nt4(const short* __restrict__ A,
                                                const short* __restrict__ B,
                                                int ld, int K, int N,
                                                float* __restrict__ out_f) {
  __shared__ short As[128 * 64];
  __shared__ short Bs[128 * 64];
  const int tid = threadIdx.x;
  const int lane = tid & 63;
  const int wid = tid >> 6;
  const int wr = wid >> 1, wc = wid & 1;
  const size_t m0 = (size_t)blockIdx.y * 128;
  const size_t n0 = (size_t)blockIdx.x * 128;
  A += (size_t)blockIdx.z * K;
  B += (size_t)blockIdx.z * K;
  f32x4 acc[4][4] = {};
  for (int k0 = 0; k0 < K; k0 += 64) {
    #pragma unroll
    for (int i = 0; i < 4; ++i) {
      const int off = i * 4096 + tid * 16;   // byte offset in 16KB tile
      const int r = off >> 7;                // tile row (128B per row)
      const int ke = (off & 127) >> 1;       // element offset in row
      stage16(A + (m0 + r) * (size_t)ld + k0 + ke, &As[off >> 1]);
      stage16(B + (n0 + r) * (size_t)ld + k0 + ke, &Bs[off >> 1]);
    }
    __syncthreads();
    #pragma unroll
    for (int kk = 0; kk < 64; kk += 32) {
      short8 af[4], bfr[4];
      const int kb = kk + (lane >> 4) * 8;
      const int rr = lane & 15;
      #pragma unroll
      for (int f = 0; f < 4; ++f) {
        af[f]  = *(const short8*)&As[(wr * 64 + f * 16 + rr) * 64 + kb];
        bfr[f] = *(const short8*)&Bs[(wc * 64 + f * 16 + rr) * 64 + kb];
      }
      #pragma unroll
      for (int fm = 0; fm < 4; ++fm)
        #pragma unroll
        for (int fn = 0; fn < 4; ++fn)
          acc[fm][fn] = __builtin_amdgcn_mfma_f32_16x16x32_bf16(af[fm], bfr[fn], acc[fm][fn], 0, 0, 0);
    }
    __syncthreads();
  }
  const int rbase = (lane >> 4) * 4;
  const int cbase = lane & 15;
  #pragma unroll
  for (int fm = 0; fm < 4; ++fm) {
    #pragma unroll
    for (int fn = 0; fn < 4; ++fn) {
      #pragma unroll
      for (int j = 0; j < 4; ++j) {
        const size_t row = m0 + wr * 64 + fm * 16 + rbase + j;
        const size_t col = n0 + wc * 64 + fn * 16 + cbase;
        if (col < 160)
          out_f[((size_t)blockIdx.z * NTOK + row) * (size_t)N + col] = acc[fm][fn][j];
      }
    }
  }
}

// ---- x_dbl epilogue: sum 4 split-K partials, split into dt_low/B/C ----
__global__ __launch_bounds__(256) void xdbl_epi_k(const float* __restrict__ part,
                                                  short* __restrict__ dtl,
                                                  float* __restrict__ Bc,
                                                  float* __restrict__ Cc) {
  const int row = blockIdx.x;
  const int col = threadIdx.x;
  if (col >= 160) return;
  const size_t i = (size_t)row * 256 + col;
  const float v = part[i] + part[(size_t)NTOK * 256 + i]
                + part[(size_t)2 * NTOK * 256 + i]
                + part[(size_t)3 * NTOK * 256 + i];
  if (col < 128)      dtl[(size_t)row * 128 + col] = f2bf(v);
  else if (col < 144) Bc[(size_t)row * 16 + (col - 128)] = v;
  else                Cc[(size_t)row * 16 + (col - 144)] = v;
}

// ------- causal depthwise conv (W=4) + SiLU, rolling window, 8 tok/thread -------
__global__ __launch_bounds__(256) void conv_silu_k(const float* __restrict__ xz,
                                                   const float* __restrict__ cw,
                                                   const float* __restrict__ cb,
                                                   short* __restrict__ xc) {
  const int d = blockIdx.x * 256 + threadIdx.x;
  const int t0 = blockIdx.y * 8;          // global token base (never crosses seq)
  const int l0 = t0 & (SEQL - 1);         // within-sequence index
  const float4 w = ((const float4*)cw)[d];
  const float bias = cb[d];
  float x0 = (l0 >= 3) ? xz[(size_t)(t0 - 3) * XZW + d] : 0.f;
  float x1 = (l0 >= 2) ? xz[(size_t)(t0 - 2) * XZW + d] : 0.f;
  float x2 = (l0 >= 1) ? xz[(size_t)(t0 - 1) * XZW + d] : 0.f;
  #pragma unroll
  for (int i = 0; i < 8; ++i) {
    const float x3 = xz[(size_t)(t0 + i) * XZW + d];
    const float acc = bias + w.x * x0 + w.y * x1 + w.z * x2 + w.w * x3;
    const float sv = acc / (1.f + __expf(-acc));
    xc[(size_t)(t0 + i) * DI + d] = f2bf(sv);
    x0 = x1; x1 = x2; x2 = x3;
  }
}

// ---------------- chunked selective scan (2 threads/chain, 8 states each) ----------------
__global__ __launch_bounds__(256) void scan1_k(const short* __restrict__ del_bf,
                                               const short* __restrict__ xc,
                                               const float* __restrict__ Bc,
                                               const float* __restrict__ alog,
                                               float* __restrict__ hloc,
                                               float* __restrict__ Ssum) {
  const int t = blockIdx.x * 256 + threadIdx.x;   // 1,048,576 threads
  const int sub = t & 1;
  const int chain = (t >> 1) & (NCHAIN - 1);      // (b,d)
  const int chunk = t >> 14;
  const int b = chain >> 12;
  const int d = chain & 4095;
  float A[8];
  #pragma unroll
  for (int j = 0; j < 8; ++j) A[j] = -__expf(alog[d * 16 + sub * 8 + j]);
  float h[8] = {};
  float S = 0.f;
  size_t token = (size_t)b * SEQL + (size_t)chunk * CL;
  #pragma unroll 2
  for (int l = 0; l < CL; ++l, ++token) {
    const float delta = bf2f(del_bf[token * DI + d]);
    const float u = bf2f(xc[token * DI + d]);
    const float du = delta * u;
    S += delta;
    const float4 B0 = ((const float4*)Bc)[token * 4 + sub * 2];
    const float4 B1 = ((const float4*)Bc)[token * 4 + sub * 2 + 1];
    const float Bv[8] = {B0.x, B0.y, B0.z, B0.w, B1.x, B1.y, B1.z, B1.w};
    #pragma unroll
    for (int j = 0; j < 8; ++j)
      h[j] = h[j] * __expf(delta * A[j]) + du * Bv[j];
  }
  const size_t idx = (size_t)(chunk * NCHAIN + chain) * 4 + sub * 2;
  ((float4*)hloc)[idx]     = make_float4(h[0], h[1], h[2], h[3]);
  ((float4*)hloc)[idx + 1] = make_float4(h[4], h[5], h[6], h[7]);
  if (sub == 0) Ssum[chunk * NCHAIN + chain] = S;
}

// pass 2: serial combine over chunks, IN-PLACE (hloc[c] becomes h_in[c])
__global__ __launch_bounds__(256) void scan2_k(float* __restrict__ hloc,
                                               const float* __restrict__ Ssum,
                                               const float* __restrict__ alog) {
  const int t = blockIdx.x * 256 + threadIdx.x;   // 32768 threads
  const int q = t & 3;
  const int chain = t >> 2;
  const int d = chain & 4095;
  float A[4];
  #pragma unroll
  for (int j = 0; j < 4; ++j) A[j] = -__expf(alog[d * 16 + q * 4 + j]);
  float4 h = make_float4(0.f, 0.f, 0.f, 0.f);
  for (int c = 0; c < NCH; ++c) {
    const size_t idx = (size_t)(c * NCHAIN + chain) * 4 + q;
    const float S = Ssum[c * NCHAIN + chain];
    const float4 hl = ((const float4*)hloc)[idx];
    ((float4*)hloc)[idx] = h;                 // publish prefix state
    h.x = h.x * __expf(A[0] * S) + hl.x;
    h.y = h.y * __expf(A[1] * S) + hl.y;
    h.z = h.z * __expf(A[2] * S) + hl.z;
    h.w = h.w * __expf(A[3] * S) + hl.w;
  }
}

// pass 3: re-scan chunk from h_in (stored in hloc), y + D-skip + z-gate -> y bf16
__global__ __launch_bounds__(256) void scan3_k(const short* __restrict__ del_bf,
                                               const short* __restrict__ xc,
                                               const float* __restrict__ Bc,
                                               const float* __restrict__ Cc,
                                               const float* __restrict__ xzbuf,
                                               const float* __restrict__ alog,
                                               const float* __restrict__ dvec,
                                               const float* __restrict__ hin,
                                               short* __restrict__ y) {
  const int t = blockIdx.x * 256 + threadIdx.x;
  const int sub = t & 1;
  const int chain = (t >> 1) & (NCHAIN - 1);
  const int chunk = t >> 14;
  const int b = chain >> 12;
  const int d = chain & 4095;
  float A[8];
  #pragma unroll
  for (int j = 0; j < 8; ++j) A[j] = -__expf(alog[d * 16 + sub * 8 + j]);
  const float Dd = dvec[d];
  const size_t idx = (size_t)(chunk * NCHAIN + chain) * 4 + sub * 2;
  const float4 h0 = ((const float4*)hin)[idx];
  const float4 h1 = ((const float4*)hin)[idx + 1];
  float h[8] = {h0.x, h0.y, h0.z, h0.w, h1.x, h1.y, h1.z, h1.w};
  size_t token = (size_t)b * SEQL + (size_t)chunk * CL;
  #pragma unroll 2
  for (int l = 0; l < CL; ++l, ++token) {
    const float delta = bf2f(del_bf[token * DI + d]);
    const float u = bf2f(xc[token * DI + d]);
    const float du = delta * u;
    const float4 B0 = ((const float4*)Bc)[token * 4 + sub * 2];
    const float4 B1 = ((const float4*)Bc)[token * 4 + sub * 2 + 1];
    const float4 C0 = ((const float4*)Cc)[token * 4 + sub * 2];
    const float4 C1 = ((const float4*)Cc)[token * 4 + sub * 2 + 1];
    const float Bv[8] = {B0.x, B0.y, B0.z, B0.w, B1.x, B1.y, B1.z, B1.w};
    const float Cv[8] = {C0.x, C0.y, C0.z, C0.w, C1.x, C1.y, C1.z, C1.w};
    float yp = 0.f;
    #pragma unroll
    for (int j = 0; j < 8; ++j) {
      h[j] = h[j] * __expf(delta * A[j]) + du * Bv[j];
      yp += h[j] * Cv[j];
    }
    yp += __shfl_xor(yp, 1);
    if (sub == 0) {
      const float z = xzbuf[token * XZW + DI + d];
      const float sz = z / (1.f + __expf(-z));
      y[token * DI + d] = f2bf((yp + u * Dd) * sz);
    }
  }
}

extern "C" void kernel_launch(void* const* d_in, const int* in_sizes, int n_in,
                              void* d_out, int out_size, void* d_ws, size_t ws_size,
                              hipStream_t stream) {
  const float* hs   = (const float*)d_in[0];   // (B,L,2048)
  const float* nsc  = (const float*)d_in[1];
  const float* win  = (const float*)d_in[2];   // (8192,2048)
  const float* cw   = (const float*)d_in[3];   // (4096,1,4)
  const float* cb   = (const float*)d_in[4];
  const float* wxp  = (const float*)d_in[5];   // (160,4096)
  const float* wdt  = (const float*)d_in[6];   // (4096,128)
  const float* bdt  = (const float*)d_in[7];
  const float* wout = (const float*)d_in[8];   // (2048,4096)
  const float* alog = (const float*)d_in[9];   // (4096,16)
  const float* dvec = (const float*)d_in[10];

  float* out0 = (float*)d_out;                       // (4096, 2048)
  float* xz   = out0 + (size_t)NTOK * DM;            // (4096, 8192)

  char* w = (char*)d_ws;
  size_t off = 0;
  auto alloc = [&](size_t bytes) {
    char* p = w + off;
    off += (bytes + 255) & ~(size_t)255;
    return p;
  };
  short* xn_bf   = (short*)alloc((size_t)NTOK * DM * 2);      // dead after gemm_big(in_proj)
  short* win_bf  = (short*)alloc((size_t)XZW * DM * 2);       // dead after gemm_big(in_proj)
  short* wout_bf = (short*)alloc((size_t)DM * DI * 2);
  short* wdt_bf  = (short*)alloc((size_t)DI * DTR * 2);
  short* wxp_bf  = (short*)alloc((size_t)256 * DI * 2);
  short* xc_bf   = (short*)alloc((size_t)NTOK * DI * 2);      // dead after scan3
  short* dtl_bf  = (short*)alloc((size_t)NTOK * DTR * 2);     // dead after dt_proj
  float* Bc      = (float*)alloc((size_t)NTOK * DST * 4);     // dead after scan3
  float* Cc      = (float*)alloc((size_t)NTOK * DST * 4);     // dead after scan3
  short* del_bf  = (short*)alloc((size_t)NTOK * DI * 2);      // dead after scan3
  short* y_bf    = (short*)alloc((size_t)NTOK * DI * 2);

  // Aliased scratch (lifetimes disjoint within one call):
  float* xp_part = (float*)win_bf;
  float* hloc    = (float*)win_bf;
  float* Ssum    = (float*)xn_bf;
  short* opart   = (short*)xc_bf;   // 2 x 16 MB bf16 partials

  // 0+1. fused weight conversions + RMSNorm
  prep_k<<<NB_CVT + NTOK, 256, 0, stream>>>(
      win, wout, wdt, wxp, hs, nsc, win_bf, wout_bf, wdt_bf, wxp_bf, xn_bf);
  // 2. xz = xn @ in_proj^T  -> d_out (output 1)
  gemm_big<8, 8, 0><<<dim3((XZW / 256) * (NTOK / 256)), 512, 0, stream>>>(
      xn_bf, win_bf, DM, DM, XZW, XZW / 256, xz, 0, nullptr, nullptr);
  // 3. causal depthwise conv + SiLU
  conv_silu_k<<<dim3(DI / 256, NTOK / 8), 256, 0, stream>>>(xz, cw, cb, xc_bf);
  // 4. x_dbl = xc @ x_proj^T, split-K x4 -> partials (160 cols) -> dt_low/B/C
  gemm_nt4<<<dim3(2, NTOK / 128, 4), 256, 0, stream>>>(
      xc_bf, wxp_bf, DI, DI / 4, 256, xp_part);
  xdbl_epi_k<<<NTOK, 256, 0, stream>>>(xp_part, dtl_bf, Bc, Cc);
  // 5. delta = softplus(dt_low @ dt_proj^T + b) -> bf16  [256x256 schedule]
  gemm_big<8, 4, 1><<<dim3((DI / 256) * (NTOK / 256)), 512, 0, stream>>>(
      dtl_bf, wdt_bf, DTR, DTR, DI, DI / 256, nullptr, 0, bdt, del_bf);
  // 6. chunked selective scan + gating -> y bf16  (2 threads/chain, CL=32)
  scan1_k<<<(NCHAIN * 2 * NCH) / 256, 256, 0, stream>>>(
      del_bf, xc_bf, Bc, alog, hloc, Ssum);
  scan2_k<<<(NCHAIN * 4) / 256, 256, 0, stream>>>(hloc, Ssum, alog);
  scan3_k<<<(NCHAIN * 2 * NCH) / 256, 256, 0, stream>>>(
      del_bf, xc_bf, Bc, Cc, xz, alog, dvec, hloc, y_bf);
  // 7. out_proj via split-K=2, bf16 partials: 128 tiles x 2 K-halves
  gemm_big<4, 4, 2><<<dim3((DM / 256) * (NTOK / 256), 2), 512, 0, stream>>>(
      y_bf, wout_bf, DI, DI / 2, DM, DM / 256, nullptr, (size_t)NTOK * DM,
      nullptr, opart);
  combine_k<<<(NTOK * DM / 4) / 256, 256, 0, stream>>>(opart, hs, out0);
}